// Round 2
// baseline (222.211 us; speedup 1.0000x reference)
//
#include <hip/hip_runtime.h>

#define GATE_SCALE 1.7015f

typedef __attribute__((ext_vector_type(8))) short short8;
typedef __attribute__((ext_vector_type(4))) float f32x4;

__device__ __forceinline__ ushort f2bf(float f) {
    union { float f; unsigned u; } v; v.f = f;
    unsigned u = v.u;
    unsigned r = (u + 0x7FFFu + ((u >> 16) & 1u)) >> 16;
    return (ushort)r;
}

__device__ __forceinline__ void gl2lds16(const void* g, void* l) {
    __builtin_amdgcn_global_load_lds((const __attribute__((address_space(1))) void*)g,
                                     (__attribute__((address_space(3))) void*)l, 16, 0, 0);
}

// ---------------------------------------------------------------------------
// Kernel 1: convert x_cat and W to bf16; tail blocks build antisymmetrized
// complex A: Ac[n][o*8+i][2]
// ---------------------------------------------------------------------------
__global__ void convert_kernel(const float* __restrict__ xr, const float* __restrict__ xi,
                               const float* __restrict__ W,
                               const float* __restrict__ Ar, const float* __restrict__ Ai,
                               ushort* __restrict__ xc, ushort* __restrict__ wb,
                               float* __restrict__ Ac) {
    int bx = blockIdx.x;
    if (bx >= 1024) {
        int v = (bx - 1024) * 256 + threadIdx.x;   // 0..8191
        if (v < 8192) {
            int n = v >> 6, t = v & 63, o = t >> 3, i = t & 7;
            const float* arn = Ar + n * 64;
            const float* ain = Ai + n * 64;
            float a_r = 0.5f * (arn[o * 8 + i] - arn[i * 8 + o]);
            float a_i = 0.5f * (ain[o * 8 + i] + ain[i * 8 + o]);
            Ac[n * 128 + t * 2]     = a_r;
            Ac[n * 128 + t * 2 + 1] = a_i;
        }
        return;
    }
    const int XCV = 2048 * 2048 / 4;
    const int WV  = 1024 * 2048 / 4;
    const int STR = 1024 * 256;
    for (int v = bx * 256 + threadIdx.x; v < XCV + WV; v += STR) {
        float4 f;
        ushort* dst;
        if (v < XCV) {
            int idx = v * 4;
            int m = idx >> 11;
            int k = idx & 2047;
            const float* s = (k < 1024) ? (xr + m * 1024 + k) : (xi + m * 1024 + k - 1024);
            f = *(const float4*)s;
            dst = xc + idx;
        } else {
            int idx = (v - XCV) * 4;
            f = *(const float4*)(W + idx);
            dst = wb + idx;
        }
        ushort4 o;
        o.x = f2bf(f.x); o.y = f2bf(f.y); o.z = f2bf(f.z); o.w = f2bf(f.w);
        *(ushort4*)dst = o;
    }
}

// ---------------------------------------------------------------------------
// Kernel 2: GEMM gate = sigmoid((xc @ W^T + b)*1.7015) + 8-col mean -> g[2048][128]
// BM=128, BN=64, BK=64; 512 threads = 8 waves (2m x 4n); double-buffered LDS,
// 2-phase prefetch (STAGE(next) before compute(cur), one barrier per tile).
// ---------------------------------------------------------------------------
__launch_bounds__(512, 2)
__global__ void gemm_gate_kernel(const ushort* __restrict__ A,   // xc [2048][2048]
                                 const ushort* __restrict__ Bw,  // wb [1024][2048]
                                 const float* __restrict__ bias, // [1024]
                                 float* __restrict__ g) {        // [2048][128]
    __shared__ __align__(16) ushort lA[2][128 * 64];
    __shared__ __align__(16) ushort lB[2][64 * 64];
    const int tid = threadIdx.x;
    const int lane = tid & 63;
    const int wid = tid >> 6;                 // 0..7
    const int m0 = blockIdx.x * 128, n0 = blockIdx.y * 64;
    const int wm = wid >> 2, wn = wid & 3;
    const int lrow = lane & 15, kgrp = (lane >> 4) * 8;

    f32x4 acc[4] = {};

    #define STAGE(buf, k0)                                                          \
        {                                                                           \
            _Pragma("unroll")                                                       \
            for (int q = 0; q < 2; ++q) {                                           \
                int c = q * 512 + tid;                                              \
                gl2lds16(&A[(m0 + (c >> 3)) * 2048 + (k0) + (c & 7) * 8],           \
                         &lA[buf][c * 8]);                                          \
            }                                                                       \
            {                                                                       \
                int c = tid;                                                        \
                gl2lds16(&Bw[(n0 + (c >> 3)) * 2048 + (k0) + (c & 7) * 8],          \
                         &lB[buf][c * 8]);                                          \
            }                                                                       \
        }

    STAGE(0, 0);
    int cur = 0;
    for (int t = 0; t < 32; ++t) {
        __syncthreads();                 // implicit vmcnt(0) drain: buf[cur] ready
        if (t < 31) STAGE(cur ^ 1, (t + 1) * 64);
        #pragma unroll
        for (int ks = 0; ks < 2; ++ks) {
            short8 af[4], bf;
            #pragma unroll
            for (int mi = 0; mi < 4; ++mi)
                af[mi] = *(const short8*)&lA[cur][(wm * 64 + mi * 16 + lrow) * 64 + ks * 32 + kgrp];
            bf = *(const short8*)&lB[cur][(wn * 16 + lrow) * 64 + ks * 32 + kgrp];
            #pragma unroll
            for (int mi = 0; mi < 4; ++mi)
                acc[mi] = __builtin_amdgcn_mfma_f32_16x16x32_bf16(af[mi], bf, acc[mi], 0, 0, 0);
        }
        cur ^= 1;
    }
    #undef STAGE

    const int rowg = (lane >> 4) * 4;
    const int dcol = n0 + wn * 16 + lrow;
    const float bv = bias[dcol];
    #pragma unroll
    for (int mi = 0; mi < 4; ++mi) {
        #pragma unroll
        for (int r = 0; r < 4; ++r) {
            int mrow = m0 + wm * 64 + mi * 16 + rowg + r;
            float z = (acc[mi][r] + bv) * GATE_SCALE;
            float gate = 1.0f / (1.0f + __expf(-z));
            gate += __shfl_xor(gate, 1);
            gate += __shfl_xor(gate, 2);
            gate += __shfl_xor(gate, 4);
            if ((lane & 7) == 0)
                g[mrow * 128 + (dcol >> 3)] = gate * 0.125f;
        }
    }
}

// ---------------------------------------------------------------------------
// Kernel 3: apply via Horner:
//   out = x + A(c1 x + A(c2 x + A(c3 x + A(c4 x)))),  c_k = 2(-g)^k
// block 256 = 32 n-lanes x 8 ml; each thread handles 2 m rows (A reuse);
// grid (4 n-chunks, 128 m-chunks) = 512 blocks. LDS = A only (16 KB, swizzled).
// ---------------------------------------------------------------------------
__launch_bounds__(256, 2)
__global__ void apply_kernel(const float* __restrict__ xr, const float* __restrict__ xi,
                             const float* __restrict__ g,   // [2048][128]
                             const float* __restrict__ Ac,  // [128][64][2]
                             float* __restrict__ outr, float* __restrict__ outi) {
    __shared__ __align__(16) float lA[4096];   // 32 n x 128 floats, swizzled
    const int tid = threadIdx.x;
    const int n0 = blockIdx.x * 32;
    const int m0 = blockIdx.y * 16;

    for (int v = tid; v < 4096; v += 256) {
        int n = v >> 7, e = v & 127;
        lA[n * 128 + (e ^ (n << 2))] = Ac[(n0 + n) * 128 + e];
    }
    __syncthreads();

    const int nl = tid & 31, ml = tid >> 5;
    const float* pa = &lA[nl * 128];
    const int sw = nl << 2;
    const int dbase = (n0 + nl) * 8;
    const int mA = m0 + ml, mB = m0 + 8 + ml;

    float vrA[8], viA[8], vrB[8], viB[8];
    {
        float4 f0 = *(const float4*)&xr[mA * 1024 + dbase];
        float4 f1 = *(const float4*)&xr[mA * 1024 + dbase + 4];
        vrA[0]=f0.x; vrA[1]=f0.y; vrA[2]=f0.z; vrA[3]=f0.w;
        vrA[4]=f1.x; vrA[5]=f1.y; vrA[6]=f1.z; vrA[7]=f1.w;
        float4 f2 = *(const float4*)&xi[mA * 1024 + dbase];
        float4 f3 = *(const float4*)&xi[mA * 1024 + dbase + 4];
        viA[0]=f2.x; viA[1]=f2.y; viA[2]=f2.z; viA[3]=f2.w;
        viA[4]=f3.x; viA[5]=f3.y; viA[6]=f3.z; viA[7]=f3.w;
        float4 f4 = *(const float4*)&xr[mB * 1024 + dbase];
        float4 f5 = *(const float4*)&xr[mB * 1024 + dbase + 4];
        vrB[0]=f4.x; vrB[1]=f4.y; vrB[2]=f4.z; vrB[3]=f4.w;
        vrB[4]=f5.x; vrB[5]=f5.y; vrB[6]=f5.z; vrB[7]=f5.w;
        float4 f6 = *(const float4*)&xi[mB * 1024 + dbase];
        float4 f7 = *(const float4*)&xi[mB * 1024 + dbase + 4];
        viB[0]=f6.x; viB[1]=f6.y; viB[2]=f6.z; viB[3]=f6.w;
        viB[4]=f7.x; viB[5]=f7.y; viB[6]=f7.z; viB[7]=f7.w;
    }

    float gA = g[mA * 128 + n0 + nl];
    float gB = g[mB * 128 + n0 + nl];
    float c1A = -2.f * gA, c2A = -c1A * gA, c3A = -c2A * gA, c4A = -c3A * gA;
    float c1B = -2.f * gB, c2B = -c1B * gB, c3B = -c2B * gB, c4B = -c3B * gB;

    float wrA[8], wiA[8], wrB[8], wiB[8];
    float trA[8], tiA[8], trB[8], tiB[8];

    // t = A * w  (complex matvec, both sites share the A reads)
    #define MATVEC()                                                                \
        _Pragma("unroll")                                                           \
        for (int o = 0; o < 8; ++o) {                                               \
            float arA = 0.f, aiA = 0.f, arB = 0.f, aiB = 0.f;                       \
            _Pragma("unroll")                                                       \
            for (int t4 = 0; t4 < 4; ++t4) {                                        \
                float4 f = *(const float4*)&pa[(o * 16 + t4 * 4) ^ sw];             \
                const int q = t4 * 2;                                               \
                arA += f.x * wrA[q]     - f.y * wiA[q];                             \
                aiA += f.x * wiA[q]     + f.y * wrA[q];                             \
                arA += f.z * wrA[q + 1] - f.w * wiA[q + 1];                         \
                aiA += f.z * wiA[q + 1] + f.w * wrA[q + 1];                         \
                arB += f.x * wrB[q]     - f.y * wiB[q];                             \
                aiB += f.x * wiB[q]     + f.y * wrB[q];                             \
                arB += f.z * wrB[q + 1] - f.w * wiB[q + 1];                         \
                aiB += f.z * wiB[q + 1] + f.w * wrB[q + 1];                         \
            }                                                                       \
            trA[o] = arA; tiA[o] = aiA; trB[o] = arB; tiB[o] = aiB;                 \
        }

    #pragma unroll
    for (int o = 0; o < 8; ++o) {
        wrA[o] = c4A * vrA[o]; wiA[o] = c4A * viA[o];
        wrB[o] = c4B * vrB[o]; wiB[o] = c4B * viB[o];
    }
    MATVEC();
    #pragma unroll
    for (int o = 0; o < 8; ++o) {
        wrA[o] = c3A * vrA[o] + trA[o]; wiA[o] = c3A * viA[o] + tiA[o];
        wrB[o] = c3B * vrB[o] + trB[o]; wiB[o] = c3B * viB[o] + tiB[o];
    }
    MATVEC();
    #pragma unroll
    for (int o = 0; o < 8; ++o) {
        wrA[o] = c2A * vrA[o] + trA[o]; wiA[o] = c2A * viA[o] + tiA[o];
        wrB[o] = c2B * vrB[o] + trB[o]; wiB[o] = c2B * viB[o] + tiB[o];
    }
    MATVEC();
    #pragma unroll
    for (int o = 0; o < 8; ++o) {
        wrA[o] = c1A * vrA[o] + trA[o]; wiA[o] = c1A * viA[o] + tiA[o];
        wrB[o] = c1B * vrB[o] + trB[o]; wiB[o] = c1B * viB[o] + tiB[o];
    }
    MATVEC();
    #undef MATVEC

    float4 s0 = {vrA[0] + trA[0], vrA[1] + trA[1], vrA[2] + trA[2], vrA[3] + trA[3]};
    float4 s1 = {vrA[4] + trA[4], vrA[5] + trA[5], vrA[6] + trA[6], vrA[7] + trA[7]};
    float4 s2 = {viA[0] + tiA[0], viA[1] + tiA[1], viA[2] + tiA[2], viA[3] + tiA[3]};
    float4 s3 = {viA[4] + tiA[4], viA[5] + tiA[5], viA[6] + tiA[6], viA[7] + tiA[7]};
    *(float4*)&outr[mA * 1024 + dbase]     = s0;
    *(float4*)&outr[mA * 1024 + dbase + 4] = s1;
    *(float4*)&outi[mA * 1024 + dbase]     = s2;
    *(float4*)&outi[mA * 1024 + dbase + 4] = s3;
    float4 s4 = {vrB[0] + trB[0], vrB[1] + trB[1], vrB[2] + trB[2], vrB[3] + trB[3]};
    float4 s5 = {vrB[4] + trB[4], vrB[5] + trB[5], vrB[6] + trB[6], vrB[7] + trB[7]};
    float4 s6 = {viB[0] + tiB[0], viB[1] + tiB[1], viB[2] + tiB[2], viB[3] + tiB[3]};
    float4 s7 = {viB[4] + tiB[4], viB[5] + tiB[5], viB[6] + tiB[6], viB[7] + tiB[7]};
    *(float4*)&outr[mB * 1024 + dbase]     = s4;
    *(float4*)&outr[mB * 1024 + dbase + 4] = s5;
    *(float4*)&outi[mB * 1024 + dbase]     = s6;
    *(float4*)&outi[mB * 1024 + dbase + 4] = s7;
}

// ---------------------------------------------------------------------------
extern "C" void kernel_launch(void* const* d_in, const int* in_sizes, int n_in,
                              void* d_out, int out_size, void* d_ws, size_t ws_size,
                              hipStream_t stream) {
    const float* xr = (const float*)d_in[0];
    const float* xi = (const float*)d_in[1];
    const float* Ar = (const float*)d_in[2];
    const float* Ai = (const float*)d_in[3];
    const float* W  = (const float*)d_in[4];
    const float* bg = (const float*)d_in[5];
    float* out = (float*)d_out;

    char* ws = (char*)d_ws;
    ushort* xc = (ushort*)(ws);                  // 8388608 B
    ushort* wb = (ushort*)(ws + 8388608);        // 4194304 B
    float*  g  = (float*) (ws + 12582912);       // 1048576 B
    float*  Ac = (float*) (ws + 13631488);       // 65536 B

    hipLaunchKernelGGL(convert_kernel, dim3(1056), dim3(256), 0, stream,
                       xr, xi, W, Ar, Ai, xc, wb, Ac);
    hipLaunchKernelGGL(gemm_gate_kernel, dim3(16, 16), dim3(512), 0, stream, xc, wb, bg, g);
    hipLaunchKernelGGL(apply_kernel, dim3(4, 128), dim3(256), 0, stream,
                       xr, xi, g, Ac, out, out + 2 * 1024 * 1024);
}

// Round 3
// 73.682 us; speedup vs baseline: 3.0158x; 3.0158x over previous
//
#include <hip/hip_runtime.h>

#define GATE_SCALE 1.7015f

typedef __attribute__((ext_vector_type(8))) short short8;
typedef __attribute__((ext_vector_type(4))) float f32x4;

__device__ __forceinline__ ushort f2bf(float f) {
    union { float f; unsigned u; } v; v.f = f;
    unsigned u = v.u;
    unsigned r = (u + 0x7FFFu + ((u >> 16) & 1u)) >> 16;
    return (ushort)r;
}

__device__ __forceinline__ void gl2lds16(const void* g, void* l) {
    __builtin_amdgcn_global_load_lds((const __attribute__((address_space(1))) void*)g,
                                     (__attribute__((address_space(3))) void*)l, 16, 0, 0);
}

// ---------------------------------------------------------------------------
// Kernel 1: convert x_cat and W to bf16; tail blocks build antisymmetrized
// complex A: Ac[n][o*8+i][2]
// ---------------------------------------------------------------------------
__global__ void convert_kernel(const float* __restrict__ xr, const float* __restrict__ xi,
                               const float* __restrict__ W,
                               const float* __restrict__ Ar, const float* __restrict__ Ai,
                               ushort* __restrict__ xc, ushort* __restrict__ wb,
                               float* __restrict__ Ac) {
    int bx = blockIdx.x;
    if (bx >= 1024) {
        int v = (bx - 1024) * 256 + threadIdx.x;   // 0..8191
        if (v < 8192) {
            int n = v >> 6, t = v & 63, o = t >> 3, i = t & 7;
            const float* arn = Ar + n * 64;
            const float* ain = Ai + n * 64;
            float a_r = 0.5f * (arn[o * 8 + i] - arn[i * 8 + o]);
            float a_i = 0.5f * (ain[o * 8 + i] + ain[i * 8 + o]);
            Ac[n * 128 + t * 2]     = a_r;
            Ac[n * 128 + t * 2 + 1] = a_i;
        }
        return;
    }
    const int XCV = 2048 * 2048 / 4;
    const int WV  = 1024 * 2048 / 4;
    const int STR = 1024 * 256;
    for (int v = bx * 256 + threadIdx.x; v < XCV + WV; v += STR) {
        float4 f;
        ushort* dst;
        if (v < XCV) {
            int idx = v * 4;
            int m = idx >> 11;
            int k = idx & 2047;
            const float* s = (k < 1024) ? (xr + m * 1024 + k) : (xi + m * 1024 + k - 1024);
            f = *(const float4*)s;
            dst = xc + idx;
        } else {
            int idx = (v - XCV) * 4;
            f = *(const float4*)(W + idx);
            dst = wb + idx;
        }
        ushort4 o;
        o.x = f2bf(f.x); o.y = f2bf(f.y); o.z = f2bf(f.z); o.w = f2bf(f.w);
        *(ushort4*)dst = o;
    }
}

// ---------------------------------------------------------------------------
// Kernel 2: GEMM gate = sigmoid((xc @ W^T + b)*1.7015) + 8-col mean -> g[2048][128]
// BM=128, BN=64, BK=64; 512 threads = 8 waves (2m x 4n); double-buffered LDS,
// 2-phase prefetch (STAGE(next) before compute(cur), one barrier per tile).
// ---------------------------------------------------------------------------
__launch_bounds__(512, 2)
__global__ void gemm_gate_kernel(const ushort* __restrict__ A,   // xc [2048][2048]
                                 const ushort* __restrict__ Bw,  // wb [1024][2048]
                                 const float* __restrict__ bias, // [1024]
                                 float* __restrict__ g) {        // [2048][128]
    __shared__ __align__(16) ushort lA[2][128 * 64];
    __shared__ __align__(16) ushort lB[2][64 * 64];
    const int tid = threadIdx.x;
    const int lane = tid & 63;
    const int wid = tid >> 6;                 // 0..7
    const int m0 = blockIdx.x * 128, n0 = blockIdx.y * 64;
    const int wm = wid >> 2, wn = wid & 3;
    const int lrow = lane & 15, kgrp = (lane >> 4) * 8;

    f32x4 acc[4] = {};

    #define STAGE(buf, k0)                                                          \
        {                                                                           \
            _Pragma("unroll")                                                       \
            for (int q = 0; q < 2; ++q) {                                           \
                int c = q * 512 + tid;                                              \
                gl2lds16(&A[(m0 + (c >> 3)) * 2048 + (k0) + (c & 7) * 8],           \
                         &lA[buf][c * 8]);                                          \
            }                                                                       \
            {                                                                       \
                int c = tid;                                                        \
                gl2lds16(&Bw[(n0 + (c >> 3)) * 2048 + (k0) + (c & 7) * 8],          \
                         &lB[buf][c * 8]);                                          \
            }                                                                       \
        }

    STAGE(0, 0);
    int cur = 0;
    for (int t = 0; t < 32; ++t) {
        __syncthreads();                 // implicit vmcnt(0) drain: buf[cur] ready
        if (t < 31) STAGE(cur ^ 1, (t + 1) * 64);
        #pragma unroll
        for (int ks = 0; ks < 2; ++ks) {
            short8 af[4], bf;
            #pragma unroll
            for (int mi = 0; mi < 4; ++mi)
                af[mi] = *(const short8*)&lA[cur][(wm * 64 + mi * 16 + lrow) * 64 + ks * 32 + kgrp];
            bf = *(const short8*)&lB[cur][(wn * 16 + lrow) * 64 + ks * 32 + kgrp];
            #pragma unroll
            for (int mi = 0; mi < 4; ++mi)
                acc[mi] = __builtin_amdgcn_mfma_f32_16x16x32_bf16(af[mi], bf, acc[mi], 0, 0, 0);
        }
        cur ^= 1;
    }
    #undef STAGE

    const int rowg = (lane >> 4) * 4;
    const int dcol = n0 + wn * 16 + lrow;
    const float bv = bias[dcol];
    #pragma unroll
    for (int mi = 0; mi < 4; ++mi) {
        #pragma unroll
        for (int r = 0; r < 4; ++r) {
            int mrow = m0 + wm * 64 + mi * 16 + rowg + r;
            float z = (acc[mi][r] + bv) * GATE_SCALE;
            float gate = 1.0f / (1.0f + __expf(-z));
            gate += __shfl_xor(gate, 1);
            gate += __shfl_xor(gate, 2);
            gate += __shfl_xor(gate, 4);
            if ((lane & 7) == 0)
                g[mrow * 128 + (dcol >> 3)] = gate * 0.125f;
        }
    }
}

// ---------------------------------------------------------------------------
// t = A * w (complex 8x8 matvec from swizzled LDS row). All loops fully
// unroll -> every array index is compile-time (keeps state in VGPRs).
// ---------------------------------------------------------------------------
__device__ __forceinline__ void cmatvec(const float* __restrict__ pa, int sw,
                                        const float* __restrict__ wr,
                                        const float* __restrict__ wi,
                                        float* __restrict__ tr,
                                        float* __restrict__ ti) {
    #pragma unroll
    for (int o = 0; o < 8; ++o) {
        float ar = 0.f, ai = 0.f;
        #pragma unroll
        for (int t4 = 0; t4 < 4; ++t4) {
            float4 f = *(const float4*)&pa[(o * 16 + t4 * 4) ^ sw];
            const int q = t4 * 2;
            ar += f.x * wr[q]     - f.y * wi[q];
            ai += f.x * wi[q]     + f.y * wr[q];
            ar += f.z * wr[q + 1] - f.w * wi[q + 1];
            ai += f.z * wi[q + 1] + f.w * wr[q + 1];
        }
        tr[o] = ar; ti[o] = ai;
    }
}

// ---------------------------------------------------------------------------
// Kernel 3: apply via Horner:
//   out = x + A(c1 x + A(c2 x + A(c3 x + A(c4 x)))),  c_k = 2(-g)^k
// One site per thread (48 floats of state -> no spills). block 256 =
// 32 n-lanes x 8 m; grid (4 n-chunks, 256 m-chunks). LDS = A only (16 KB).
// ---------------------------------------------------------------------------
__launch_bounds__(256)
__global__ void apply_kernel(const float* __restrict__ xr, const float* __restrict__ xi,
                             const float* __restrict__ g,   // [2048][128]
                             const float* __restrict__ Ac,  // [128][64][2]
                             float* __restrict__ outr, float* __restrict__ outi) {
    __shared__ __align__(16) float lA[4096];   // 32 n x 128 floats, swizzled
    const int tid = threadIdx.x;
    const int n0 = blockIdx.x * 32;
    const int m0 = blockIdx.y * 8;

    #pragma unroll
    for (int it = 0; it < 4; ++it) {
        int v = it * 256 + tid;                // float4 id, 0..1023
        int n = v >> 5, e4 = (v & 31) << 2;
        *(float4*)&lA[n * 128 + (e4 ^ (n << 2))] = *(const float4*)&Ac[(n0 + n) * 128 + e4];
    }
    __syncthreads();

    const int nl = tid & 31, ml = tid >> 5;
    const float* pa = &lA[nl * 128];
    const int sw = nl << 2;
    const int dbase = (n0 + nl) * 8;
    const int m = m0 + ml;

    float vr[8], vi[8], wr[8], wi[8], tr[8], ti[8];
    {
        float4 f0 = *(const float4*)&xr[m * 1024 + dbase];
        float4 f1 = *(const float4*)&xr[m * 1024 + dbase + 4];
        vr[0]=f0.x; vr[1]=f0.y; vr[2]=f0.z; vr[3]=f0.w;
        vr[4]=f1.x; vr[5]=f1.y; vr[6]=f1.z; vr[7]=f1.w;
        float4 f2 = *(const float4*)&xi[m * 1024 + dbase];
        float4 f3 = *(const float4*)&xi[m * 1024 + dbase + 4];
        vi[0]=f2.x; vi[1]=f2.y; vi[2]=f2.z; vi[3]=f2.w;
        vi[4]=f3.x; vi[5]=f3.y; vi[6]=f3.z; vi[7]=f3.w;
    }

    const float gv = g[m * 128 + n0 + nl];
    const float c1 = -2.f * gv, c2 = -c1 * gv, c3 = -c2 * gv, c4 = -c3 * gv;

    #pragma unroll
    for (int o = 0; o < 8; ++o) { wr[o] = c4 * vr[o]; wi[o] = c4 * vi[o]; }
    cmatvec(pa, sw, wr, wi, tr, ti);
    #pragma unroll
    for (int o = 0; o < 8; ++o) { wr[o] = c3 * vr[o] + tr[o]; wi[o] = c3 * vi[o] + ti[o]; }
    cmatvec(pa, sw, wr, wi, tr, ti);
    #pragma unroll
    for (int o = 0; o < 8; ++o) { wr[o] = c2 * vr[o] + tr[o]; wi[o] = c2 * vi[o] + ti[o]; }
    cmatvec(pa, sw, wr, wi, tr, ti);
    #pragma unroll
    for (int o = 0; o < 8; ++o) { wr[o] = c1 * vr[o] + tr[o]; wi[o] = c1 * vi[o] + ti[o]; }
    cmatvec(pa, sw, wr, wi, tr, ti);

    float4 s0 = {vr[0] + tr[0], vr[1] + tr[1], vr[2] + tr[2], vr[3] + tr[3]};
    float4 s1 = {vr[4] + tr[4], vr[5] + tr[5], vr[6] + tr[6], vr[7] + tr[7]};
    float4 s2 = {vi[0] + ti[0], vi[1] + ti[1], vi[2] + ti[2], vi[3] + ti[3]};
    float4 s3 = {vi[4] + ti[4], vi[5] + ti[5], vi[6] + ti[6], vi[7] + ti[7]};
    *(float4*)&outr[m * 1024 + dbase]     = s0;
    *(float4*)&outr[m * 1024 + dbase + 4] = s1;
    *(float4*)&outi[m * 1024 + dbase]     = s2;
    *(float4*)&outi[m * 1024 + dbase + 4] = s3;
}

// ---------------------------------------------------------------------------
extern "C" void kernel_launch(void* const* d_in, const int* in_sizes, int n_in,
                              void* d_out, int out_size, void* d_ws, size_t ws_size,
                              hipStream_t stream) {
    const float* xr = (const float*)d_in[0];
    const float* xi = (const float*)d_in[1];
    const float* Ar = (const float*)d_in[2];
    const float* Ai = (const float*)d_in[3];
    const float* W  = (const float*)d_in[4];
    const float* bg = (const float*)d_in[5];
    float* out = (float*)d_out;

    char* ws = (char*)d_ws;
    ushort* xc = (ushort*)(ws);                  // 8388608 B
    ushort* wb = (ushort*)(ws + 8388608);        // 4194304 B
    float*  g  = (float*) (ws + 12582912);       // 1048576 B
    float*  Ac = (float*) (ws + 13631488);       // 65536 B

    hipLaunchKernelGGL(convert_kernel, dim3(1056), dim3(256), 0, stream,
                       xr, xi, W, Ar, Ai, xc, wb, Ac);
    hipLaunchKernelGGL(gemm_gate_kernel, dim3(16, 16), dim3(512), 0, stream, xc, wb, bg, g);
    hipLaunchKernelGGL(apply_kernel, dim3(4, 256), dim3(256), 0, stream,
                       xr, xi, g, Ac, out, out + 2 * 1024 * 1024);
}

// Round 4
// 61.091 us; speedup vs baseline: 3.6374x; 1.2061x over previous
//
#include <hip/hip_runtime.h>

#define GATE_SCALE 1.7015f

typedef __attribute__((ext_vector_type(8))) short short8;
typedef __attribute__((ext_vector_type(4))) float f32x4;

__device__ __forceinline__ ushort f2bf(float f) {
    union { float f; unsigned u; } v; v.f = f;
    unsigned u = v.u;
    unsigned r = (u + 0x7FFFu + ((u >> 16) & 1u)) >> 16;
    return (ushort)r;
}

__device__ __forceinline__ void gl2lds16(const void* g, void* l) {
    __builtin_amdgcn_global_load_lds((const __attribute__((address_space(1))) void*)g,
                                     (__attribute__((address_space(3))) void*)l, 16, 0, 0);
}

// ---------------------------------------------------------------------------
// Kernel 1: convert x_cat and W to bf16; tail blocks build antisymmetrized
// complex A: Ac[n][o*8+i][2]
// ---------------------------------------------------------------------------
__global__ void convert_kernel(const float* __restrict__ xr, const float* __restrict__ xi,
                               const float* __restrict__ W,
                               const float* __restrict__ Ar, const float* __restrict__ Ai,
                               ushort* __restrict__ xc, ushort* __restrict__ wb,
                               float* __restrict__ Ac) {
    int bx = blockIdx.x;
    if (bx >= 1024) {
        int v = (bx - 1024) * 256 + threadIdx.x;   // 0..8191
        if (v < 8192) {
            int n = v >> 6, t = v & 63, o = t >> 3, i = t & 7;
            const float* arn = Ar + n * 64;
            const float* ain = Ai + n * 64;
            float a_r = 0.5f * (arn[o * 8 + i] - arn[i * 8 + o]);
            float a_i = 0.5f * (ain[o * 8 + i] + ain[i * 8 + o]);
            Ac[n * 128 + t * 2]     = a_r;
            Ac[n * 128 + t * 2 + 1] = a_i;
        }
        return;
    }
    const int XCV = 2048 * 2048 / 4;
    const int WV  = 1024 * 2048 / 4;
    const int STR = 1024 * 256;
    for (int v = bx * 256 + threadIdx.x; v < XCV + WV; v += STR) {
        float4 f;
        ushort* dst;
        if (v < XCV) {
            int idx = v * 4;
            int m = idx >> 11;
            int k = idx & 2047;
            const float* s = (k < 1024) ? (xr + m * 1024 + k) : (xi + m * 1024 + k - 1024);
            f = *(const float4*)s;
            dst = xc + idx;
        } else {
            int idx = (v - XCV) * 4;
            f = *(const float4*)(W + idx);
            dst = wb + idx;
        }
        ushort4 o;
        o.x = f2bf(f.x); o.y = f2bf(f.y); o.z = f2bf(f.z); o.w = f2bf(f.w);
        *(ushort4*)dst = o;
    }
}

// ---------------------------------------------------------------------------
// Kernel 2: GEMM gate = sigmoid((xc @ W^T + b)*1.7015) + 8-col mean -> g[2048][128]
// Tile 128x64, BK=64, 512 thr = 8 waves mapped 2m x 2n x 2k (K-split halves
// LDS-read duplication). LDS XOR-swizzled (T2, via pre-swizzled global src:
// rule 21) -> conflict-free ds_read_b128. K-reduction via LDS at end.
// ---------------------------------------------------------------------------
__launch_bounds__(512)
__global__ void gemm_gate_kernel(const ushort* __restrict__ A,   // xc [2048][2048]
                                 const ushort* __restrict__ Bw,  // wb [1024][2048]
                                 const float* __restrict__ bias, // [1024]
                                 float* __restrict__ g) {        // [2048][128]
    __shared__ __align__(16) ushort lA[2][128 * 64];
    __shared__ __align__(16) ushort lB[2][64 * 64];
    const int tid = threadIdx.x;
    const int lane = tid & 63;
    const int wid = tid >> 6;
    const int m0 = blockIdx.x * 128, n0 = blockIdx.y * 64;
    const int wm = wid >> 2, wn = (wid >> 1) & 1, wk = wid & 1;
    const int lrow = lane & 15, kgrp = (lane >> 4) * 8;
    const int kslot = (wk * 32 + kgrp) >> 3;      // 16B-slot index in row, 0..7

    f32x4 acc[4][2] = {};

    // Stage with source-side XOR swizzle: LDS slot (row, s) holds global
    // k-chunk s ^ (row&7); reads apply the same XOR -> banks fully spread.
    #define STAGE(buf, k0)                                                          \
        {                                                                           \
            _Pragma("unroll")                                                       \
            for (int q = 0; q < 2; ++q) {                                           \
                int c = q * 512 + tid;                                              \
                int row = c >> 3, ks = (c & 7) ^ (row & 7);                         \
                gl2lds16(&A[(m0 + row) * 2048 + (k0) + ks * 8], &lA[buf][c * 8]);   \
            }                                                                       \
            {                                                                       \
                int c = tid;                                                        \
                int row = c >> 3, ks = (c & 7) ^ (row & 7);                         \
                gl2lds16(&Bw[(n0 + row) * 2048 + (k0) + ks * 8], &lB[buf][c * 8]);  \
            }                                                                       \
        }

    STAGE(0, 0);
    int cur = 0;
    for (int t = 0; t < 32; ++t) {
        __syncthreads();
        if (t < 31) STAGE(cur ^ 1, (t + 1) * 64);
        short8 af[4], bf[2];
        #pragma unroll
        for (int mi = 0; mi < 4; ++mi) {
            int row = wm * 64 + mi * 16 + lrow;
            af[mi] = *(const short8*)&lA[cur][row * 64 + ((kslot ^ (row & 7)) << 3)];
        }
        #pragma unroll
        for (int ni = 0; ni < 2; ++ni) {
            int row = wn * 32 + ni * 16 + lrow;
            bf[ni] = *(const short8*)&lB[cur][row * 64 + ((kslot ^ (row & 7)) << 3)];
        }
        #pragma unroll
        for (int mi = 0; mi < 4; ++mi)
            #pragma unroll
            for (int ni = 0; ni < 2; ++ni)
                acc[mi][ni] = __builtin_amdgcn_mfma_f32_16x16x32_bf16(af[mi], bf[ni], acc[mi][ni], 0, 0, 0);
        cur ^= 1;
    }
    #undef STAGE

    // ---- cross-wave K reduction (wk=1 partials -> wk=0) ----
    __syncthreads();                       // all LDS reads of lA/lB done
    float* lacc = (float*)&lA[0][0];       // 32 KB = 128x64 f32
    const int rowg = (lane >> 4) * 4;
    if (wk == 1) {
        #pragma unroll
        for (int mi = 0; mi < 4; ++mi)
            #pragma unroll
            for (int ni = 0; ni < 2; ++ni)
                #pragma unroll
                for (int r = 0; r < 4; ++r)
                    lacc[(wm * 64 + mi * 16 + rowg + r) * 64 + wn * 32 + ni * 16 + lrow] =
                        acc[mi][ni][r];
    }
    __syncthreads();
    if (wk == 0) {
        #pragma unroll
        for (int mi = 0; mi < 4; ++mi) {
            #pragma unroll
            for (int ni = 0; ni < 2; ++ni) {
                const int dcol = n0 + wn * 32 + ni * 16 + lrow;
                const float bv = bias[dcol];
                #pragma unroll
                for (int r = 0; r < 4; ++r) {
                    const int rl = wm * 64 + mi * 16 + rowg + r;
                    float z = (acc[mi][ni][r] +
                               lacc[rl * 64 + wn * 32 + ni * 16 + lrow] + bv) * GATE_SCALE;
                    float gate = 1.0f / (1.0f + __expf(-z));
                    gate += __shfl_xor(gate, 1);
                    gate += __shfl_xor(gate, 2);
                    gate += __shfl_xor(gate, 4);
                    if ((lane & 7) == 0)
                        g[(m0 + rl) * 128 + (dcol >> 3)] = gate * 0.125f;
                }
            }
        }
    }
}

// ---------------------------------------------------------------------------
// Kernel 3: apply via Horner, zero LDS. Two lanes per site: lane h owns
// output rows h*4..h*4+3; A-block (4x8 complex) lives in 64 VGPRs, gathered
// once per block from L2-resident Ac. w-half exchanged via __shfl_xor(.,1)
// (DPP). x loads perfectly coalesced float4 (d = lane*4).
//   out = x + A(c1 x + A(c2 x + A(c3 x + A(c4 x)))),  c_k = 2(-g)^k
// block 256 thr = 4 waves; wave = 32 n x 2 h, 2 m-rows per wave.
// grid (4 n-chunks, 256 m-chunks).
// ---------------------------------------------------------------------------
__launch_bounds__(256)
__global__ void apply_kernel(const float* __restrict__ xr, const float* __restrict__ xi,
                             const float* __restrict__ g,   // [2048][128]
                             const float* __restrict__ Ac,  // [128][64][2]
                             float* __restrict__ outr, float* __restrict__ outi) {
    const int tid = threadIdx.x;
    const int lane = tid & 63;
    const int wv = tid >> 6;
    const int nl = lane >> 1, h = lane & 1;
    const int n = blockIdx.x * 32 + nl;
    const int mbase = blockIdx.y * 8 + wv * 2;

    // Gather A rows h*4..h*4+3. Local j order: jj<4 = own-half cols
    // (i = h*4+jj), jj>=4 = other-half cols (i = (1-h)*4+jj-4).
    float Ar_[4][8], Ai_[4][8];
    const float* An = Ac + n * 128;
    #pragma unroll
    for (int r = 0; r < 4; ++r) {
        const int o = h * 4 + r;
        #pragma unroll
        for (int p = 0; p < 2; ++p) {
            float4 f = *(const float4*)&An[o * 16 + h * 8 + p * 4];
            Ar_[r][p * 2]     = f.x;  Ai_[r][p * 2]     = f.y;
            Ar_[r][p * 2 + 1] = f.z;  Ai_[r][p * 2 + 1] = f.w;
        }
        #pragma unroll
        for (int p = 0; p < 2; ++p) {
            float4 f = *(const float4*)&An[o * 16 + (1 - h) * 8 + p * 4];
            Ar_[r][4 + p * 2]     = f.x;  Ai_[r][4 + p * 2]     = f.y;
            Ar_[r][4 + p * 2 + 1] = f.z;  Ai_[r][4 + p * 2 + 1] = f.w;
        }
    }

    // t = A * w ; own half from registers, other half from partner lane.
    #define CMV()                                                                   \
        {                                                                           \
            float pwr[4], pwi[4];                                                   \
            _Pragma("unroll")                                                       \
            for (int k2 = 0; k2 < 4; ++k2) {                                        \
                pwr[k2] = __shfl_xor(wr[k2], 1);                                    \
                pwi[k2] = __shfl_xor(wi[k2], 1);                                    \
            }                                                                       \
            _Pragma("unroll")                                                       \
            for (int r = 0; r < 4; ++r) {                                           \
                float sr = 0.f, si = 0.f;                                           \
                _Pragma("unroll")                                                   \
                for (int jj = 0; jj < 4; ++jj) {                                    \
                    sr += Ar_[r][jj] * wr[jj]      - Ai_[r][jj] * wi[jj];           \
                    si += Ar_[r][jj] * wi[jj]      + Ai_[r][jj] * wr[jj];           \
                    sr += Ar_[r][4 + jj] * pwr[jj] - Ai_[r][4 + jj] * pwi[jj];      \
                    si += Ar_[r][4 + jj] * pwi[jj] + Ai_[r][4 + jj] * pwr[jj];      \
                }                                                                   \
                tr[r] = sr; ti[r] = si;                                             \
            }                                                                       \
        }

    #pragma unroll
    for (int mi = 0; mi < 2; ++mi) {
        const int m = mbase + mi;
        const int d = n * 8 + h * 4;
        const float4 fvr = *(const float4*)&xr[m * 1024 + d];
        const float4 fvi = *(const float4*)&xi[m * 1024 + d];
        float vr[4] = {fvr.x, fvr.y, fvr.z, fvr.w};
        float vi[4] = {fvi.x, fvi.y, fvi.z, fvi.w};
        const float gv = g[m * 128 + n];
        const float c1 = -2.f * gv, c2 = -c1 * gv, c3 = -c2 * gv, c4 = -c3 * gv;
        float wr[4], wi[4], tr[4], ti[4];

        #pragma unroll
        for (int r = 0; r < 4; ++r) { wr[r] = c4 * vr[r]; wi[r] = c4 * vi[r]; }
        CMV();
        #pragma unroll
        for (int r = 0; r < 4; ++r) { wr[r] = c3 * vr[r] + tr[r]; wi[r] = c3 * vi[r] + ti[r]; }
        CMV();
        #pragma unroll
        for (int r = 0; r < 4; ++r) { wr[r] = c2 * vr[r] + tr[r]; wi[r] = c2 * vi[r] + ti[r]; }
        CMV();
        #pragma unroll
        for (int r = 0; r < 4; ++r) { wr[r] = c1 * vr[r] + tr[r]; wi[r] = c1 * vi[r] + ti[r]; }
        CMV();

        float4 s0 = {vr[0] + tr[0], vr[1] + tr[1], vr[2] + tr[2], vr[3] + tr[3]};
        float4 s1 = {vi[0] + ti[0], vi[1] + ti[1], vi[2] + ti[2], vi[3] + ti[3]};
        *(float4*)&outr[m * 1024 + d] = s0;
        *(float4*)&outi[m * 1024 + d] = s1;
    }
    #undef CMV
}

// ---------------------------------------------------------------------------
extern "C" void kernel_launch(void* const* d_in, const int* in_sizes, int n_in,
                              void* d_out, int out_size, void* d_ws, size_t ws_size,
                              hipStream_t stream) {
    const float* xr = (const float*)d_in[0];
    const float* xi = (const float*)d_in[1];
    const float* Ar = (const float*)d_in[2];
    const float* Ai = (const float*)d_in[3];
    const float* W  = (const float*)d_in[4];
    const float* bg = (const float*)d_in[5];
    float* out = (float*)d_out;

    char* ws = (char*)d_ws;
    ushort* xc = (ushort*)(ws);                  // 8388608 B
    ushort* wb = (ushort*)(ws + 8388608);        // 4194304 B
    float*  g  = (float*) (ws + 12582912);       // 1048576 B
    float*  Ac = (float*) (ws + 13631488);       // 65536 B

    hipLaunchKernelGGL(convert_kernel, dim3(1056), dim3(256), 0, stream,
                       xr, xi, W, Ar, Ai, xc, wb, Ac);
    hipLaunchKernelGGL(gemm_gate_kernel, dim3(16, 16), dim3(512), 0, stream, xc, wb, bg, g);
    hipLaunchKernelGGL(apply_kernel, dim3(4, 256), dim3(256), 0, stream,
                       xr, xi, g, Ac, out, out + 2 * 1024 * 1024);
}